// Round 9
// baseline (280.446 us; speedup 1.0000x reference)
//
#include <hip/hip_runtime.h>
#include <math.h>

// MultiChannelXi: xi[b,t,k,:] = sum_{s<=t} alpha_k^(t-s) h[b,s,:] / Z_{k,t}
// alpha = clip(sigmoid(raw_alpha), 1e-6, 1-1e-6),
// Z_{k,t} = (1 - alpha^(t+1)) / (1 - alpha).
//
// SINGLE-PASS decoupled-lookback chunked scan (Merrill-Garland at chunk
// granularity). One kernel: read h once (registers), write out once.
//   phase 1: L[k] = chunk aggregate (Horner over 16 rows held in VGPRs);
//            publish lbuf + flag=1 (release, agent scope).
//   phase 2: lookback over predecessors in 16-wide windows; aggregates are
//            consumed with explicit weights aC^i (order-independent =>
//            parallel loads); terminate at any inclusive (flag=2).
//   phase 3: publish inclusive I = L + aC*S (flag=2).
//   phase 4: rescan from registers, normalize, NT-store out.
// Ticket remap: block id taken from a global atomic counter => predecessor
// tickets were grabbed by already-running blocks => they publish flag=1 in
// bounded time (no waits precede publication) => no deadlock regardless of
// dispatch order or residency. flags+ticket re-zeroed per launch via
// hipMemsetAsync (graph-capture safe; harness itself uses memsets).
// Lessons: r2/r4 grid.sync latency trap; r7/r8: 4-kernel split converged
// at ~52us (h read twice + 16MB ws round trips + 3 graph gaps).

namespace {

constexpr int T_LEN  = 4096;
constexpr int D_DIM  = 512;
constexpr int D4     = D_DIM / 4;      // 128 float4 lanes per row
constexpr int K_CH   = 4;
constexpr int CHUNK  = 16;
constexpr int NCHUNK = T_LEN / CHUNK;  // 256
constexpr int WND    = 16;             // lookback window (<= 64 lanes)

typedef float floatx4 __attribute__((ext_vector_type(4)));

__device__ __forceinline__ float sigmoid_clip(float x) {
    float a = 1.0f / (1.0f + expf(-x));
    return fminf(fmaxf(a, 1e-6f), 1.0f - 1e-6f);
}

// d = a*d + x   (Horner step)
__device__ __forceinline__ void fma4(float4& d, float a, const float4& x) {
    d.x = fmaf(a, d.x, x.x);
    d.y = fmaf(a, d.y, x.y);
    d.z = fmaf(a, d.z, x.z);
    d.w = fmaf(a, d.w, x.w);
}
// d += w*x      (weighted accumulate)
__device__ __forceinline__ void acc4(float4& d, float w, const float4& x) {
    d.x = fmaf(w, x.x, d.x);
    d.y = fmaf(w, x.y, d.y);
    d.z = fmaf(w, x.z, d.z);
    d.w = fmaf(w, x.w, d.w);
}

__device__ __forceinline__ float4 nt_load4(const float4* p) {
    floatx4 v = __builtin_nontemporal_load(reinterpret_cast<const floatx4*>(p));
    float4 r; r.x = v.x; r.y = v.y; r.z = v.z; r.w = v.w;
    return r;
}
__device__ __forceinline__ void nt_store4(float4* p, const float4& v) {
    floatx4 nv; nv.x = v.x; nv.y = v.y; nv.z = v.z; nv.w = v.w;
    __builtin_nontemporal_store(nv, reinterpret_cast<floatx4*>(p));
}

__global__ void __launch_bounds__(128)
ema_lookback(const float4* __restrict__ h4,
             const float*  __restrict__ raw_alpha,
             unsigned int* __restrict__ flags,    // [B*NCHUNK], 0/1/2
             unsigned int* __restrict__ ticket,   // [1]
             float4* __restrict__ lbuf,           // [B][NCHUNK][K][D4] aggregates
             float4* __restrict__ pbuf,           // [B][NCHUNK][K][D4] inclusives
             float4* __restrict__ out4)           // [B][T][K][D4]
{
    // ---- ticket remap: virtual block id in grab order ----
    __shared__ unsigned int vid_sm;
    if (threadIdx.x == 0) vid_sm = atomicAdd(ticket, 1u);
    __syncthreads();
    const unsigned int vid = vid_sm;
    const int c  = (int)(vid % NCHUNK);
    const int b  = (int)(vid / NCHUNK);
    const int d4 = threadIdx.x;
    const int lane = threadIdx.x & 63;
    const int t0 = c * CHUNK;

    float al[K_CH], aC[K_CH];
#pragma unroll
    for (int k = 0; k < K_CH; ++k) {
        al[k] = sigmoid_clip(raw_alpha[k]);
        aC[k] = exp2f((float)CHUNK * log2f(al[k]));  // alpha^CHUNK
    }

    // ---- phase 1: h chunk -> registers (NT); aggregate L[k]; publish ----
    float4 hreg[CHUNK];
    {
        const float4* hp = h4 + ((size_t)b * T_LEN + t0) * D4 + d4;
#pragma unroll
        for (int j = 0; j < CHUNK; ++j) hreg[j] = nt_load4(hp + (size_t)j * D4);
    }
    float4 L[K_CH];
#pragma unroll
    for (int k = 0; k < K_CH; ++k) L[k] = make_float4(0.f, 0.f, 0.f, 0.f);
#pragma unroll
    for (int j = 0; j < CHUNK; ++j) {
#pragma unroll
        for (int k = 0; k < K_CH; ++k) fma4(L[k], al[k], hreg[j]);
    }
    const size_t lbase = (((size_t)b * NCHUNK + c) * K_CH) * D4 + d4;
#pragma unroll
    for (int k = 0; k < K_CH; ++k) lbuf[lbase + (size_t)k * D4] = L[k];
    __syncthreads();
    if (threadIdx.x == 0) {
        __threadfence();
        __hip_atomic_store(&flags[b * NCHUNK + c], 1u,
                           __ATOMIC_RELEASE, __HIP_MEMORY_SCOPE_AGENT);
    }

    // ---- phase 2: decoupled lookback ----
    float4 S[K_CH];
#pragma unroll
    for (int k = 0; k < K_CH; ++k) S[k] = make_float4(0.f, 0.f, 0.f, 0.f);
    float wk[K_CH] = {1.f, 1.f, 1.f, 1.f};   // aC^(consumed so far)

    const float4* lb = lbuf + ((size_t)b * NCHUNK * K_CH) * D4 + d4;
    const float4* pb = pbuf + ((size_t)b * NCHUNK * K_CH) * D4 + d4;
    const unsigned int* fb = flags + b * NCHUNK;

    int jw = c - 1;
    while (jw >= 0) {
        const int avail = jw + 1;
        const int W = avail < WND ? avail : WND;
        unsigned int f = 1u;
        if (lane < W)
            f = __hip_atomic_load(&fb[jw - lane],
                                  __ATOMIC_ACQUIRE, __HIP_MEMORY_SCOPE_AGENT);
        const unsigned long long m2 = __ballot(lane < W && f == 2u);
        const unsigned long long m0 = __ballot(lane < W && f == 0u);
        const int n2 = m2 ? (__ffsll((unsigned long long)m2) - 1) : W;
        const int n0 = m0 ? (__ffsll((unsigned long long)m0) - 1) : W;
        const bool incl = (n2 < n0);
        const int  nagg = incl ? n2 : n0;

        // consume aggregates at distances 0..nagg-1 (order-independent)
        for (int i = 0; i < nagg; ++i) {
            const size_t off = ((size_t)(jw - i) * K_CH) * D4;
#pragma unroll
            for (int k = 0; k < K_CH; ++k) {
                acc4(S[k], wk[k], lb[off + (size_t)k * D4]);
            }
#pragma unroll
            for (int k = 0; k < K_CH; ++k) wk[k] *= aC[k];
        }
        if (incl) {
            const size_t off = ((size_t)(jw - nagg) * K_CH) * D4;
#pragma unroll
            for (int k = 0; k < K_CH; ++k)
                acc4(S[k], wk[k], pb[off + (size_t)k * D4]);
            break;
        }
        jw -= nagg;
        if (nagg == 0) __builtin_amdgcn_s_sleep(2);
    }

    // ---- phase 3: publish inclusive I = L + aC*S ----
#pragma unroll
    for (int k = 0; k < K_CH; ++k) {
        float4 I;
        I.x = fmaf(aC[k], S[k].x, L[k].x);
        I.y = fmaf(aC[k], S[k].y, L[k].y);
        I.z = fmaf(aC[k], S[k].z, L[k].z);
        I.w = fmaf(aC[k], S[k].w, L[k].w);
        pbuf[lbase + (size_t)k * D4] = I;
    }
    __syncthreads();
    if (threadIdx.x == 0) {
        __threadfence();
        __hip_atomic_store(&flags[b * NCHUNK + c], 2u,
                           __ATOMIC_RELEASE, __HIP_MEMORY_SCOPE_AGENT);
    }

    // ---- phase 4: rescan from registers, normalize, NT-store ----
    float om[K_CH], pw[K_CH];
#pragma unroll
    for (int k = 0; k < K_CH; ++k) {
        om[k] = 1.0f - al[k];
        pw[k] = exp2f((float)(t0 + 1) * log2f(al[k]));  // alpha^(t+1) at j=0
    }
    float4* op = out4 + (((size_t)b * T_LEN + t0) * (size_t)K_CH) * D4 + d4;
#pragma unroll
    for (int j = 0; j < CHUNK; ++j) {
#pragma unroll
        for (int k = 0; k < K_CH; ++k) {
            fma4(S[k], al[k], hreg[j]);
            const float invZ = om[k] / fmaxf(1.0f - pw[k], 1e-30f);
            float4 o;
            o.x = S[k].x * invZ;
            o.y = S[k].y * invZ;
            o.z = S[k].z * invZ;
            o.w = S[k].w * invZ;
            nt_store4(&op[((size_t)j * K_CH + k) * D4], o);
            pw[k] *= al[k];
        }
    }
}

} // namespace

extern "C" void kernel_launch(void* const* d_in, const int* in_sizes, int n_in,
                              void* d_out, int out_size, void* d_ws, size_t ws_size,
                              hipStream_t stream)
{
    const float4* h4        = (const float4*)d_in[0];
    const float*  raw_alpha = (const float*)d_in[1];
    float4* out4 = (float4*)d_out;

    const int B = in_sizes[0] / (T_LEN * D_DIM);  // 4

    // ws layout: [flags: B*NCHUNK u32][ticket: u32][pad to 8KB][lbuf 8MB][pbuf 8MB]
    unsigned int* flags  = (unsigned int*)d_ws;
    unsigned int* ticket = flags + (size_t)B * NCHUNK;
    float4* lbuf = (float4*)((char*)d_ws + 8192);
    float4* pbuf = lbuf + (size_t)B * NCHUNK * K_CH * D4;

    // re-zero flags + ticket every launch (deterministic across graph replays)
    hipMemsetAsync(d_ws, 0, 8192, stream);

    hipLaunchKernelGGL(ema_lookback, dim3(B * NCHUNK), dim3(D4), 0, stream,
                       h4, raw_alpha, flags, ticket, lbuf, pbuf, out4);
}